// Round 7
// baseline (769.192 us; speedup 1.0000x reference)
//
#include <hip/hip_runtime.h>

typedef unsigned short u16;
typedef unsigned int u32;
typedef __bf16 bf16x8 __attribute__((ext_vector_type(8)));
typedef float f32x4 __attribute__((ext_vector_type(4)));

#define MFMA_BF16(a, b, c) __builtin_amdgcn_mfma_f32_16x16x32_bf16(a, b, c, 0, 0, 0)

#define NBUC_MAX 512
#define BCAP 4608
#define EPB 8192  // edges staged per block in bucket_scatter

__device__ __forceinline__ float bf2f(u16 h) {
  u32 u = ((u32)h) << 16;
  return __builtin_bit_cast(float, u);
}
__device__ __forceinline__ u16 f2bf(float f) {
  u32 u = __builtin_bit_cast(u32, f);
  u += 0x7fffu + ((u >> 16) & 1u);
  return (u16)(u >> 16);
}

// ---- weight prep: 6 conv weights fp32 [k][n] -> bf16 transposed [n][k], one dispatch
__global__ __launch_bounds__(256) void prep_w6(const float* __restrict__ w0,
                                               const float* __restrict__ w1,
                                               const float* __restrict__ w2,
                                               const float* __restrict__ w3,
                                               const float* __restrict__ w4,
                                               const float* __restrict__ w5,
                                               u16* __restrict__ wt) {
  const int which = blockIdx.x >> 6;
  const float* w = which == 0 ? w0 : which == 1 ? w1 : which == 2 ? w2
                  : which == 3 ? w3 : which == 4 ? w4 : w5;
  int t = (blockIdx.x & 63) * 256 + threadIdx.x;  // 16384 elems per matrix
  int n = t >> 7, k = t & 127;
  wt[which * 16384 + n * 128 + k] = f2bf(w[k * 128 + n]);
}

// ---- initial MLP applied to the 500-row embedding table (h0 = table2[x])
__global__ __launch_bounds__(128) void mlp0_table(
    const float* __restrict__ emb, const float* __restrict__ w1, const float* __restrict__ b1,
    const float* __restrict__ w2, const float* __restrict__ b2, u16* __restrict__ table) {
  __shared__ float e[128];
  __shared__ float tt[128];
  int r = blockIdx.x, j = threadIdx.x;
  e[j] = emb[r * 128 + j];
  __syncthreads();
  float s = b1[j];
  for (int k = 0; k < 128; ++k) s += e[k] * w1[k * 128 + j];
  tt[j] = s > 0.f ? s : 0.f;
  __syncthreads();
  float s2 = b2[j];
  for (int k = 0; k < 128; ++k) s2 += tt[k] * w2[k * 128 + j];
  table[r * 128 + j] = f2bf(s2);
}

// ---- pass 1: scatter edges into coarse dst-buckets (dst>>8), packed (src<<8)|dloc.
__global__ __launch_bounds__(256) void bucket_scatter(const int* __restrict__ src,
                                                      const int* __restrict__ dst,
                                                      u32* __restrict__ pairs,
                                                      u32* __restrict__ cursor, int E_, int nbuc) {
  __shared__ u32 sv[EPB];
  __shared__ u16 sb[EPB];
  __shared__ u32 lcnt[NBUC_MAX];
  __shared__ u32 lbase[NBUC_MAX];
  const int t = threadIdx.x;
  for (int b = t; b < NBUC_MAX; b += 256) lcnt[b] = 0;
  __syncthreads();
  const int e0 = blockIdx.x * EPB;
#pragma unroll
  for (int it = 0; it < EPB / 256; ++it) {
    int idx = it * 256 + t;
    int e = e0 + idx;
    u32 v = 0u;
    u16 b = 0xffffu;
    if (e < E_) {
      int s = src[e], d = dst[e];
      b = (u16)(d >> 8);
      v = ((u32)s << 8) | (u32)(d & 255);
      atomicAdd(&lcnt[b], 1u);
    }
    sv[idx] = v;
    sb[idx] = b;
  }
  __syncthreads();
  for (int b = t; b < nbuc; b += 256) {
    u32 c = lcnt[b];
    lbase[b] = c ? atomicAdd(&cursor[b], c) : 0u;
    lcnt[b] = 0;
  }
  __syncthreads();
#pragma unroll
  for (int it = 0; it < EPB / 256; ++it) {
    int idx = it * 256 + t;
    u16 b = sb[idx];
    if (b != 0xffffu) {
      u32 r = atomicAdd(&lcnt[b], 1u);
      u32 p = lbase[b] + r;
      if (p < BCAP) pairs[(size_t)b * BCAP + p] = sv[idx];
    }
  }
}

// ---- pass 2: per-bucket exact CSR (256 nodes/bucket): LDS count + scan + rank scatter
__global__ __launch_bounds__(256) void csr_build(const u32* __restrict__ pairs,
                                                 const u32* __restrict__ cursor,
                                                 u32* __restrict__ csr, int* __restrict__ RS,
                                                 int* __restrict__ DEG, int nrows) {
  __shared__ u32 cnt[256];
  __shared__ u32 offs[256];
  __shared__ u32 basearr[256];
  const int b = blockIdx.x, t = threadIdx.x;
  u32 count = cursor[b];
  if (count > BCAP) count = BCAP;
  cnt[t] = 0;
  __syncthreads();
  const u32* pb = pairs + (size_t)b * BCAP;
  for (u32 i = t; i < count; i += 256) atomicAdd(&cnt[pb[i] & 255u], 1u);
  __syncthreads();
  const u32 my = cnt[t];
  offs[t] = my;
  __syncthreads();
  for (int d = 1; d < 256; d <<= 1) {
    u32 v = (t >= d) ? offs[t - d] : 0u;
    __syncthreads();
    offs[t] += v;
    __syncthreads();
  }
  const u32 excl = offs[t] - my;  // exclusive prefix
  const int node = (b << 8) + t;
  if (node < nrows) {
    RS[node] = b * BCAP + (int)excl;
    DEG[node] = (int)my;
  }
  basearr[t] = excl;
  cnt[t] = 0;
  __syncthreads();
  for (u32 i = t; i < count; i += 256) {
    u32 v = pb[i];
    u32 dl = v & 255u;
    u32 r = atomicAdd(&cnt[dl], 1u);
    csr[(size_t)b * BCAP + basearr[dl] + r] = v >> 8;
  }
}

// ---- aggregation: AGG[i] = f(row(i)) + sum_j f(row(j))
// MODE 0: row(i) = TBL[x[i]] (layer 0, no BN).  MODE 1: row(i) = H[i], f = BN-affine+relu
// with scale/shift PRECOMPUTED in scsh (global; bn_reduce) — inline LDS recompute cost
// 1.6M bank conflicts in round 6.  32-bit byte offsets (H is 25.6 MB) cut the 64-bit
// address chains.  One wave/node; 16 lanes x dwordx4; 4 groups, 2-deep pipeline
// (round 6's 8-wide predication was net-negative: 69.6 -> 73.6 us).
template <int MODE>
__global__ __launch_bounds__(256) void agg_kernel(
    const u16* __restrict__ Hsrc, const int* __restrict__ x, const u32* __restrict__ csr,
    const int* __restrict__ RS, const int* __restrict__ DEG, const float* __restrict__ scsh,
    u16* __restrict__ AGG, int nrows) {
  int node = blockIdx.x * 4 + (threadIdx.x >> 6);
  if (node >= nrows) return;
  const int lane = threadIdx.x & 63;
  const int grp = lane >> 4;  // neighbor sub-slot 0..3
  const int fl = lane & 15;   // 16B feature chunk
  const int deg = DEG[node];
  const u32* cl = csr + RS[node];
  const char* Hb = (const char*)Hsrc;
  const u32 flo = (u32)fl << 4;

  float sc[8], sh[8];
  if (MODE == 1) {
#pragma unroll
    for (int i = 0; i < 8; ++i) {
      sc[i] = scsh[fl * 8 + i];
      sh[i] = scsh[128 + fl * 8 + i];
    }
  }
  float a[8];
#pragma unroll
  for (int i = 0; i < 8; ++i) a[i] = 0.f;

#define ACCUM(vv)                                   \
  {                                                 \
    const u16* p = (const u16*)&(vv);               \
    _Pragma("unroll") for (int i = 0; i < 8; ++i) { \
      float xv = bf2f(p[i]);                        \
      if (MODE == 1) {                              \
        xv = xv * sc[i] + sh[i];                    \
        xv = xv > 0.f ? xv : 0.f;                   \
      }                                             \
      a[i] += xv;                                   \
    }                                               \
  }
#define ROWOFF(idx) ((((u32)(MODE == 0 ? x[(idx)] : (idx))) << 8) + flo)

  if (grp == 0) {
    uint4 v = *(const uint4*)(Hb + ROWOFF(node));
    ACCUM(v);
  }
  int j = grp;
  int cA = (j < deg) ? (int)cl[j] : 0;
  int cB = (j + 4 < deg) ? (int)cl[j + 4] : 0;
  uint4 nv = make_uint4(0u, 0u, 0u, 0u);
  if (j < deg) nv = *(const uint4*)(Hb + ROWOFF(cA));
  while (j < deg) {
    uint4 cv = nv;
    int cn = cB;
    cB = (j + 8 < deg) ? (int)cl[j + 8] : 0;
    if (j + 4 < deg) nv = *(const uint4*)(Hb + ROWOFF(cn));
    ACCUM(cv);
    j += 4;
  }
#undef ROWOFF
#undef ACCUM

#pragma unroll
  for (int i = 0; i < 8; ++i) {
    a[i] += __shfl_xor(a[i], 16);
    a[i] += __shfl_xor(a[i], 32);
  }
  if (grp == 0) {
    u32 o[4];
#pragma unroll
    for (int i = 0; i < 4; ++i) o[i] = (u32)f2bf(a[2 * i]) | ((u32)f2bf(a[2 * i + 1]) << 16);
    *(uint4*)(AGG + (size_t)node * 128 + fl * 8) = *(uint4*)o;
  }
}

// ---- fused 2-layer MLP (bf16 MFMA), 64-row x 128-col tile per block, 4 waves
// Y = relu(X@W1+b1)@W2+b2 ; per-column sum/sumsq -> PART[block][256] (contention-free;
// the 256-address global atomics made 1563-deep serial chains in rounds 2-6).
__global__ __launch_bounds__(256) void mlp_kernel(
    const u16* __restrict__ X, const u16* __restrict__ W1t, const float* __restrict__ b1,
    const u16* __restrict__ W2t, const float* __restrict__ b2, u16* __restrict__ Y,
    float* __restrict__ part, int nrows) {
  __shared__ u16 Xs[64 * 136];
  __shared__ u16 Ts[64 * 136];
  const int t = threadIdx.x;
  const int row0 = blockIdx.x * 64;
  {
    const int seg = t & 15;
    const int rb = t >> 4;
#pragma unroll
    for (int p = 0; p < 4; ++p) {
      const int r = rb + p * 16;
      const int gr = row0 + r;
      uint4 v = make_uint4(0u, 0u, 0u, 0u);
      if (gr < nrows) v = *(const uint4*)(X + (size_t)gr * 128 + seg * 8);
      *(uint4*)(Xs + r * 136 + seg * 8) = v;
    }
  }
  __syncthreads();
  const int lane = t & 63;
  const int wave = t >> 6;
  const int n0 = wave * 32;
  const int nl = lane & 15;
  const int quad = lane >> 4;

  bf16x8 bw[2][4];
#pragma unroll
  for (int nt = 0; nt < 2; ++nt)
#pragma unroll
    for (int kk = 0; kk < 4; ++kk)
      bw[nt][kk] = *(const bf16x8*)(W1t + (size_t)(n0 + nt * 16 + nl) * 128 + kk * 32 + quad * 8);

  f32x4 acc[4][2];
#pragma unroll
  for (int mt = 0; mt < 4; ++mt) {
    acc[mt][0] = (f32x4)0.0f;
    acc[mt][1] = (f32x4)0.0f;
  }
#pragma unroll
  for (int kk = 0; kk < 4; ++kk) {
#pragma unroll
    for (int mt = 0; mt < 4; ++mt) {
      bf16x8 a = *(const bf16x8*)(Xs + (mt * 16 + nl) * 136 + kk * 32 + quad * 8);
      acc[mt][0] = MFMA_BF16(a, bw[0][kk], acc[mt][0]);
      acc[mt][1] = MFMA_BF16(a, bw[1][kk], acc[mt][1]);
    }
  }
  // epilogue 1: bias + relu -> Ts (bf16)
#pragma unroll
  for (int nt = 0; nt < 2; ++nt) {
    const int n = n0 + nt * 16 + nl;
    const float bias = b1[n];
#pragma unroll
    for (int mt = 0; mt < 4; ++mt)
#pragma unroll
      for (int r = 0; r < 4; ++r) {
        float v = acc[mt][nt][r] + bias;
        v = v > 0.f ? v : 0.f;
        Ts[(mt * 16 + quad * 4 + r) * 136 + n] = f2bf(v);
      }
  }
  __syncthreads();
  // GEMM2
#pragma unroll
  for (int nt = 0; nt < 2; ++nt)
#pragma unroll
    for (int kk = 0; kk < 4; ++kk)
      bw[nt][kk] = *(const bf16x8*)(W2t + (size_t)(n0 + nt * 16 + nl) * 128 + kk * 32 + quad * 8);
#pragma unroll
  for (int mt = 0; mt < 4; ++mt) {
    acc[mt][0] = (f32x4)0.0f;
    acc[mt][1] = (f32x4)0.0f;
  }
#pragma unroll
  for (int kk = 0; kk < 4; ++kk) {
#pragma unroll
    for (int mt = 0; mt < 4; ++mt) {
      bf16x8 a = *(const bf16x8*)(Ts + (mt * 16 + nl) * 136 + kk * 32 + quad * 8);
      acc[mt][0] = MFMA_BF16(a, bw[0][kk], acc[mt][0]);
      acc[mt][1] = MFMA_BF16(a, bw[1][kk], acc[mt][1]);
    }
  }
  // epilogue 2: bias, store Y (bf16), per-block BN partials
  float ssum[2] = {0.f, 0.f}, ssq[2] = {0.f, 0.f};
#pragma unroll
  for (int nt = 0; nt < 2; ++nt) {
    const int n = n0 + nt * 16 + nl;
    const float bias = b2[n];
#pragma unroll
    for (int mt = 0; mt < 4; ++mt)
#pragma unroll
      for (int r = 0; r < 4; ++r) {
        const int row = row0 + mt * 16 + quad * 4 + r;
        float v = acc[mt][nt][r] + bias;
        if (row < nrows) {
          Y[(size_t)row * 128 + n] = f2bf(v);
          ssum[nt] += v;
          ssq[nt] += v * v;
        }
      }
  }
#pragma unroll
  for (int nt = 0; nt < 2; ++nt) {
    float s = ssum[nt], q = ssq[nt];
    s += __shfl_xor(s, 16);
    q += __shfl_xor(q, 16);
    s += __shfl_xor(s, 32);
    q += __shfl_xor(q, 32);
    if (quad == 0) {
      const int n = n0 + nt * 16 + nl;
      part[(size_t)blockIdx.x * 256 + n] = s;
      part[(size_t)blockIdx.x * 256 + 128 + n] = q;
    }
  }
}

// ---- reduce per-block BN partials -> scale/shift (one block, 1024 threads)
__global__ __launch_bounds__(1024) void bn_reduce(const float* __restrict__ part, int nblk,
                                                  const float* __restrict__ g,
                                                  const float* __restrict__ be, float invN,
                                                  float* __restrict__ scsh) {
  __shared__ float red[4][256];
  const int t = threadIdx.x;
  const int col = t & 255;
  const int rg = t >> 8;  // 0..3
  float s = 0.f;
  for (int b = rg; b < nblk; b += 4) s += part[(size_t)b * 256 + col];
  red[rg][col] = s;
  __syncthreads();
  if (rg == 0) red[0][col] = red[0][col] + red[1][col] + red[2][col] + red[3][col];
  __syncthreads();
  if (t < 128) {
    float mu = red[0][t] * invN;
    float var = red[0][128 + t] * invN - mu * mu;
    float rstd = rsqrtf(var + 1e-5f);
    float sc = rstd * g[t];
    scsh[t] = sc;
    scsh[128 + t] = be[t] - mu * sc;
  }
}

// ---- pooling (fused layer-3 BN+relu via precomputed scsh) + final head, one block/graph
__global__ __launch_bounds__(256) void pool_final(
    const u16* __restrict__ Hh, const int* __restrict__ batch, const float* __restrict__ scsh,
    const float* __restrict__ f1w, const float* __restrict__ f1b, const float* __restrict__ f2w,
    const float* __restrict__ f2b, float* __restrict__ out, int nrows) {
  __shared__ float red[16][128];
  __shared__ float pr[128];
  __shared__ float tt[128];
  const int gid = blockIdx.x, t = threadIdx.x;
  int l = 0, r = nrows;
  while (l < r) {
    int m = (l + r) >> 1;
    if (batch[m] < gid) l = m + 1; else r = m;
  }
  const int s0 = l;
  r = nrows;
  while (l < r) {
    int m = (l + r) >> 1;
    if (batch[m] < gid + 1) l = m + 1; else r = m;
  }
  const int s1 = l;
  const int fl = t & 15;
  const int grp = t >> 4;
  float sc[8], sh[8];
#pragma unroll
  for (int i = 0; i < 8; ++i) {
    sc[i] = scsh[fl * 8 + i];
    sh[i] = scsh[128 + fl * 8 + i];
  }
  float a[8];
#pragma unroll
  for (int i = 0; i < 8; ++i) a[i] = 0.f;
  for (int i = s0 + grp; i < s1; i += 16) {
    uint4 v = *(const uint4*)(Hh + (size_t)i * 128 + fl * 8);
    const u16* pp = (const u16*)&v;
#pragma unroll
    for (int k = 0; k < 8; ++k) {
      float xv = bf2f(pp[k]) * sc[k] + sh[k];
      a[k] += xv > 0.f ? xv : 0.f;
    }
  }
#pragma unroll
  for (int k = 0; k < 8; ++k) red[grp][fl * 8 + k] = a[k];
  __syncthreads();
  if (t < 128) {
    float s = 0.f;
#pragma unroll
    for (int gg2 = 0; gg2 < 16; ++gg2) s += red[gg2][t];
    pr[t] = s;
  }
  __syncthreads();
  if (t < 128) {
    float s = f1b[t];
    for (int k = 0; k < 128; ++k) s += pr[k] * f1w[k * 128 + t];
    tt[t] = s > 0.f ? s : 0.f;
  }
  __syncthreads();
  if (t < 10) {
    float s2 = f2b[t];
    for (int k = 0; k < 128; ++k) s2 += tt[k] * f2w[k * 10 + t];
    out[gid * 10 + t] = s2;
  }
}

// ws layout (bytes):
//   H     @ 0          : 25,600,000  (bf16 node features)
//   AGG   @ 25,600,000 : 25,600,000  (bf16 aggregated, layer input tiles)
//   PAIRS @ 51,200,000 : 512*4608*4 = 9,437,184
//   CSR   @ 60,637,184 : 9,437,184
//   RS    @ 70,074,368 : 400,000
//   DEG   @ 70,474,368 : 400,000
//   CUR   @ 70,874,368 : 2,048       (zeroed)
//   SCSH  @ 70,876,416 : 3,072       (3 layers x 256 f32; written by bn_reduce)
//   WT    @ 70,879,488 : 196,608
//   TBL   @ 71,076,096 : 128,000
//   PART  @ 71,204,096 : 1563*256*4 = 1,600,512 (per-block BN partials; fully overwritten)
extern "C" void kernel_launch(void* const* d_in, const int* in_sizes, int n_in, void* d_out,
                              int out_size, void* d_ws, size_t ws_size, hipStream_t stream) {
  const int* x = (const int*)d_in[0];
  const int* ei = (const int*)d_in[1];
  const int* batch = (const int*)d_in[2];
  const float* emb = (const float*)d_in[3];
  const float* iw1 = (const float*)d_in[4];
  const float* ib1 = (const float*)d_in[5];
  const float* iw2 = (const float*)d_in[6];
  const float* ib2 = (const float*)d_in[7];
  const float* f1w = (const float*)d_in[8];
  const float* f1b = (const float*)d_in[9];
  const float* f2w = (const float*)d_in[10];
  const float* f2b = (const float*)d_in[11];
  const float* cw1[3] = {(const float*)d_in[12], (const float*)d_in[18], (const float*)d_in[24]};
  const float* cb1[3] = {(const float*)d_in[13], (const float*)d_in[19], (const float*)d_in[25]};
  const float* cw2[3] = {(const float*)d_in[14], (const float*)d_in[20], (const float*)d_in[26]};
  const float* cb2[3] = {(const float*)d_in[15], (const float*)d_in[21], (const float*)d_in[27]};
  const float* gg[3] = {(const float*)d_in[16], (const float*)d_in[22], (const float*)d_in[28]};
  const float* bb[3] = {(const float*)d_in[17], (const float*)d_in[23], (const float*)d_in[29]};

  const int N_ = in_sizes[0];
  const int E_ = in_sizes[1] / 2;
  const int V_ = in_sizes[3] / 128;
  const int G_ = out_size / 10;
  const int NBUC = (N_ + 255) >> 8;
  const float invN = 1.0f / (float)N_;

  char* ws = (char*)d_ws;
  u16* H = (u16*)(ws + 0);
  u16* AGG = (u16*)(ws + 25600000);
  u32* PAIRS = (u32*)(ws + 51200000);
  u32* CSR = (u32*)(ws + 60637184);
  int* RS = (int*)(ws + 70074368);
  int* DEG = (int*)(ws + 70474368);
  u32* CUR = (u32*)(ws + 70874368);
  float* SCSH = (float*)(ws + 70876416);
  u16* WT = (u16*)(ws + 70879488);
  u16* TBL = (u16*)(ws + 71076096);
  float* PART = (float*)(ws + 71204096);

  hipMemsetAsync(ws + 70874368, 0, 2048, stream);  // CUR only

  prep_w6<<<384, 256, 0, stream>>>(cw1[0], cw2[0], cw1[1], cw2[1], cw1[2], cw2[2], WT);
  mlp0_table<<<V_, 128, 0, stream>>>(emb, iw1, ib1, iw2, ib2, TBL);
  bucket_scatter<<<(E_ + EPB - 1) / EPB, 256, 0, stream>>>(ei, ei + E_, PAIRS, CUR, E_, NBUC);
  csr_build<<<NBUC, 256, 0, stream>>>(PAIRS, CUR, CSR, RS, DEG, N_);

  const int ablk = (N_ + 3) / 4;
  const int mblk = (N_ + 63) / 64;
  for (int l = 0; l < 3; ++l) {
    const u16* W1 = WT + (size_t)l * 32768;
    const u16* W2 = WT + (size_t)l * 32768 + 16384;
    if (l == 0)
      agg_kernel<0><<<ablk, 256, 0, stream>>>(TBL, x, CSR, RS, DEG, nullptr, AGG, N_);
    else
      agg_kernel<1><<<ablk, 256, 0, stream>>>(H, nullptr, CSR, RS, DEG, SCSH + (l - 1) * 256,
                                              AGG, N_);
    mlp_kernel<<<mblk, 256, 0, stream>>>(AGG, W1, cb1[l], W2, cb2[l], H, PART, N_);
    bn_reduce<<<1, 1024, 0, stream>>>(PART, mblk, gg[l], bb[l], invN, SCSH + l * 256);
  }
  pool_final<<<G_, 256, 0, stream>>>(H, batch, SCSH + 2 * 256, f1w, f1b, f2w, f2b,
                                     (float*)d_out, N_);
}

// Round 8
// 543.285 us; speedup vs baseline: 1.4158x; 1.4158x over previous
//
#include <hip/hip_runtime.h>

typedef unsigned short u16;
typedef unsigned int u32;
typedef __bf16 bf16x8 __attribute__((ext_vector_type(8)));
typedef float f32x4 __attribute__((ext_vector_type(4)));

#define MFMA_BF16(a, b, c) __builtin_amdgcn_mfma_f32_16x16x32_bf16(a, b, c, 0, 0, 0)

#define NBUC_MAX 512
#define BCAP 4608
#define EPB 8192  // edges staged per block in bucket_scatter

__device__ __forceinline__ float bf2f(u16 h) {
  u32 u = ((u32)h) << 16;
  return __builtin_bit_cast(float, u);
}
__device__ __forceinline__ u16 f2bf(float f) {
  u32 u = __builtin_bit_cast(u32, f);
  u += 0x7fffu + ((u >> 16) & 1u);
  return (u16)(u >> 16);
}

// ---- weight prep: 6 conv weights fp32 [k][n] -> bf16 transposed [n][k], one dispatch
__global__ __launch_bounds__(256) void prep_w6(const float* __restrict__ w0,
                                               const float* __restrict__ w1,
                                               const float* __restrict__ w2,
                                               const float* __restrict__ w3,
                                               const float* __restrict__ w4,
                                               const float* __restrict__ w5,
                                               u16* __restrict__ wt) {
  const int which = blockIdx.x >> 6;
  const float* w = which == 0 ? w0 : which == 1 ? w1 : which == 2 ? w2
                  : which == 3 ? w3 : which == 4 ? w4 : w5;
  int t = (blockIdx.x & 63) * 256 + threadIdx.x;  // 16384 elems per matrix
  int n = t >> 7, k = t & 127;
  wt[which * 16384 + n * 128 + k] = f2bf(w[k * 128 + n]);
}

// ---- initial MLP applied to the 500-row embedding table (h0 = table2[x])
__global__ __launch_bounds__(128) void mlp0_table(
    const float* __restrict__ emb, const float* __restrict__ w1, const float* __restrict__ b1,
    const float* __restrict__ w2, const float* __restrict__ b2, u16* __restrict__ table) {
  __shared__ float e[128];
  __shared__ float tt[128];
  int r = blockIdx.x, j = threadIdx.x;
  e[j] = emb[r * 128 + j];
  __syncthreads();
  float s = b1[j];
  for (int k = 0; k < 128; ++k) s += e[k] * w1[k * 128 + j];
  tt[j] = s > 0.f ? s : 0.f;
  __syncthreads();
  float s2 = b2[j];
  for (int k = 0; k < 128; ++k) s2 += tt[k] * w2[k * 128 + j];
  table[r * 128 + j] = f2bf(s2);
}

// ---- pass 1: scatter edges into coarse dst-buckets (dst>>8), packed (src<<8)|dloc.
__global__ __launch_bounds__(256) void bucket_scatter(const int* __restrict__ src,
                                                      const int* __restrict__ dst,
                                                      u32* __restrict__ pairs,
                                                      u32* __restrict__ cursor, int E_, int nbuc) {
  __shared__ u32 sv[EPB];
  __shared__ u16 sb[EPB];
  __shared__ u32 lcnt[NBUC_MAX];
  __shared__ u32 lbase[NBUC_MAX];
  const int t = threadIdx.x;
  for (int b = t; b < NBUC_MAX; b += 256) lcnt[b] = 0;
  __syncthreads();
  const int e0 = blockIdx.x * EPB;
#pragma unroll
  for (int it = 0; it < EPB / 256; ++it) {
    int idx = it * 256 + t;
    int e = e0 + idx;
    u32 v = 0u;
    u16 b = 0xffffu;
    if (e < E_) {
      int s = src[e], d = dst[e];
      b = (u16)(d >> 8);
      v = ((u32)s << 8) | (u32)(d & 255);
      atomicAdd(&lcnt[b], 1u);
    }
    sv[idx] = v;
    sb[idx] = b;
  }
  __syncthreads();
  for (int b = t; b < nbuc; b += 256) {
    u32 c = lcnt[b];
    lbase[b] = c ? atomicAdd(&cursor[b], c) : 0u;
    lcnt[b] = 0;
  }
  __syncthreads();
#pragma unroll
  for (int it = 0; it < EPB / 256; ++it) {
    int idx = it * 256 + t;
    u16 b = sb[idx];
    if (b != 0xffffu) {
      u32 r = atomicAdd(&lcnt[b], 1u);
      u32 p = lbase[b] + r;
      if (p < BCAP) pairs[(size_t)b * BCAP + p] = sv[idx];
    }
  }
}

// ---- pass 2: per-bucket exact CSR (256 nodes/bucket): LDS count + scan + rank scatter
__global__ __launch_bounds__(256) void csr_build(const u32* __restrict__ pairs,
                                                 const u32* __restrict__ cursor,
                                                 u32* __restrict__ csr, int* __restrict__ RS,
                                                 int* __restrict__ DEG, int nrows) {
  __shared__ u32 cnt[256];
  __shared__ u32 offs[256];
  __shared__ u32 basearr[256];
  const int b = blockIdx.x, t = threadIdx.x;
  u32 count = cursor[b];
  if (count > BCAP) count = BCAP;
  cnt[t] = 0;
  __syncthreads();
  const u32* pb = pairs + (size_t)b * BCAP;
  for (u32 i = t; i < count; i += 256) atomicAdd(&cnt[pb[i] & 255u], 1u);
  __syncthreads();
  const u32 my = cnt[t];
  offs[t] = my;
  __syncthreads();
  for (int d = 1; d < 256; d <<= 1) {
    u32 v = (t >= d) ? offs[t - d] : 0u;
    __syncthreads();
    offs[t] += v;
    __syncthreads();
  }
  const u32 excl = offs[t] - my;  // exclusive prefix
  const int node = (b << 8) + t;
  if (node < nrows) {
    RS[node] = b * BCAP + (int)excl;
    DEG[node] = (int)my;
  }
  basearr[t] = excl;
  cnt[t] = 0;
  __syncthreads();
  for (u32 i = t; i < count; i += 256) {
    u32 v = pb[i];
    u32 dl = v & 255u;
    u32 r = atomicAdd(&cnt[dl], 1u);
    csr[(size_t)b * BCAP + basearr[dl] + r] = v >> 8;
  }
}

// ---- aggregation: AGG[i] = f(row(i)) + sum_j f(row(j))
// MODE 0: row(i) = TBL[x[i]] (layer 0, no BN).  MODE 1: row(i) = H[i], f = BN-affine+relu
// with scale/shift PRECOMPUTED in scsh (global, by bn_finalize). 32-bit byte offsets
// (H is 25.6 MB). One wave/node; 16 lanes x dwordx4; 4 groups, 2-deep pipeline.
template <int MODE>
__global__ __launch_bounds__(256) void agg_kernel(
    const u16* __restrict__ Hsrc, const int* __restrict__ x, const u32* __restrict__ csr,
    const int* __restrict__ RS, const int* __restrict__ DEG, const float* __restrict__ scsh,
    u16* __restrict__ AGG, int nrows) {
  int node = blockIdx.x * 4 + (threadIdx.x >> 6);
  if (node >= nrows) return;
  const int lane = threadIdx.x & 63;
  const int grp = lane >> 4;  // neighbor sub-slot 0..3
  const int fl = lane & 15;   // 16B feature chunk
  const int deg = DEG[node];
  const u32* cl = csr + RS[node];
  const char* Hb = (const char*)Hsrc;
  const u32 flo = (u32)fl << 4;

  float sc[8], sh[8];
  if (MODE == 1) {
#pragma unroll
    for (int i = 0; i < 8; ++i) {
      sc[i] = scsh[fl * 8 + i];
      sh[i] = scsh[128 + fl * 8 + i];
    }
  }
  float a[8];
#pragma unroll
  for (int i = 0; i < 8; ++i) a[i] = 0.f;

#define ACCUM(vv)                                   \
  {                                                 \
    const u16* p = (const u16*)&(vv);               \
    _Pragma("unroll") for (int i = 0; i < 8; ++i) { \
      float xv = bf2f(p[i]);                        \
      if (MODE == 1) {                              \
        xv = xv * sc[i] + sh[i];                    \
        xv = xv > 0.f ? xv : 0.f;                   \
      }                                             \
      a[i] += xv;                                   \
    }                                               \
  }
#define ROWOFF(idx) ((((u32)(MODE == 0 ? x[(idx)] : (idx))) << 8) + flo)

  if (grp == 0) {
    uint4 v = *(const uint4*)(Hb + ROWOFF(node));
    ACCUM(v);
  }
  int j = grp;
  int cA = (j < deg) ? (int)cl[j] : 0;
  int cB = (j + 4 < deg) ? (int)cl[j + 4] : 0;
  uint4 nv = make_uint4(0u, 0u, 0u, 0u);
  if (j < deg) nv = *(const uint4*)(Hb + ROWOFF(cA));
  while (j < deg) {
    uint4 cv = nv;
    int cn = cB;
    cB = (j + 8 < deg) ? (int)cl[j + 8] : 0;
    if (j + 4 < deg) nv = *(const uint4*)(Hb + ROWOFF(cn));
    ACCUM(cv);
    j += 4;
  }
#undef ROWOFF
#undef ACCUM

#pragma unroll
  for (int i = 0; i < 8; ++i) {
    a[i] += __shfl_xor(a[i], 16);
    a[i] += __shfl_xor(a[i], 32);
  }
  if (grp == 0) {
    u32 o[4];
#pragma unroll
    for (int i = 0; i < 4; ++i) o[i] = (u32)f2bf(a[2 * i]) | ((u32)f2bf(a[2 * i + 1]) << 16);
    *(uint4*)(AGG + (size_t)node * 128 + fl * 8) = *(uint4*)o;
  }
}

// ---- fused 2-layer MLP (bf16 MFMA), 64-row x 128-col tile per block, 4 waves
// Y = relu(X@W1+b1)@W2+b2 ; per-column sum/sumsq via same-address global atomics
// (PROVEN cheap in round 6; the "contention-free" PART+1-block-reduce cost 318 us in r7).
__global__ __launch_bounds__(256) void mlp_kernel(
    const u16* __restrict__ X, const u16* __restrict__ W1t, const float* __restrict__ b1,
    const u16* __restrict__ W2t, const float* __restrict__ b2, u16* __restrict__ Y,
    float* __restrict__ stats, int nrows) {
  __shared__ u16 Xs[64 * 136];
  __shared__ u16 Ts[64 * 136];
  const int t = threadIdx.x;
  const int row0 = blockIdx.x * 64;
  {
    const int seg = t & 15;
    const int rb = t >> 4;
#pragma unroll
    for (int p = 0; p < 4; ++p) {
      const int r = rb + p * 16;
      const int gr = row0 + r;
      uint4 v = make_uint4(0u, 0u, 0u, 0u);
      if (gr < nrows) v = *(const uint4*)(X + (size_t)gr * 128 + seg * 8);
      *(uint4*)(Xs + r * 136 + seg * 8) = v;
    }
  }
  __syncthreads();
  const int lane = t & 63;
  const int wave = t >> 6;
  const int n0 = wave * 32;
  const int nl = lane & 15;
  const int quad = lane >> 4;

  bf16x8 bw[2][4];
#pragma unroll
  for (int nt = 0; nt < 2; ++nt)
#pragma unroll
    for (int kk = 0; kk < 4; ++kk)
      bw[nt][kk] = *(const bf16x8*)(W1t + (size_t)(n0 + nt * 16 + nl) * 128 + kk * 32 + quad * 8);

  f32x4 acc[4][2];
#pragma unroll
  for (int mt = 0; mt < 4; ++mt) {
    acc[mt][0] = (f32x4)0.0f;
    acc[mt][1] = (f32x4)0.0f;
  }
#pragma unroll
  for (int kk = 0; kk < 4; ++kk) {
#pragma unroll
    for (int mt = 0; mt < 4; ++mt) {
      bf16x8 a = *(const bf16x8*)(Xs + (mt * 16 + nl) * 136 + kk * 32 + quad * 8);
      acc[mt][0] = MFMA_BF16(a, bw[0][kk], acc[mt][0]);
      acc[mt][1] = MFMA_BF16(a, bw[1][kk], acc[mt][1]);
    }
  }
  // epilogue 1: bias + relu -> Ts (bf16)
#pragma unroll
  for (int nt = 0; nt < 2; ++nt) {
    const int n = n0 + nt * 16 + nl;
    const float bias = b1[n];
#pragma unroll
    for (int mt = 0; mt < 4; ++mt)
#pragma unroll
      for (int r = 0; r < 4; ++r) {
        float v = acc[mt][nt][r] + bias;
        v = v > 0.f ? v : 0.f;
        Ts[(mt * 16 + quad * 4 + r) * 136 + n] = f2bf(v);
      }
  }
  __syncthreads();
  // GEMM2
#pragma unroll
  for (int nt = 0; nt < 2; ++nt)
#pragma unroll
    for (int kk = 0; kk < 4; ++kk)
      bw[nt][kk] = *(const bf16x8*)(W2t + (size_t)(n0 + nt * 16 + nl) * 128 + kk * 32 + quad * 8);
#pragma unroll
  for (int mt = 0; mt < 4; ++mt) {
    acc[mt][0] = (f32x4)0.0f;
    acc[mt][1] = (f32x4)0.0f;
  }
#pragma unroll
  for (int kk = 0; kk < 4; ++kk) {
#pragma unroll
    for (int mt = 0; mt < 4; ++mt) {
      bf16x8 a = *(const bf16x8*)(Ts + (mt * 16 + nl) * 136 + kk * 32 + quad * 8);
      acc[mt][0] = MFMA_BF16(a, bw[0][kk], acc[mt][0]);
      acc[mt][1] = MFMA_BF16(a, bw[1][kk], acc[mt][1]);
    }
  }
  // epilogue 2: bias, store Y (bf16), BN stats
  float ssum[2] = {0.f, 0.f}, ssq[2] = {0.f, 0.f};
#pragma unroll
  for (int nt = 0; nt < 2; ++nt) {
    const int n = n0 + nt * 16 + nl;
    const float bias = b2[n];
#pragma unroll
    for (int mt = 0; mt < 4; ++mt)
#pragma unroll
      for (int r = 0; r < 4; ++r) {
        const int row = row0 + mt * 16 + quad * 4 + r;
        float v = acc[mt][nt][r] + bias;
        if (row < nrows) {
          Y[(size_t)row * 128 + n] = f2bf(v);
          ssum[nt] += v;
          ssq[nt] += v * v;
        }
      }
  }
#pragma unroll
  for (int nt = 0; nt < 2; ++nt) {
    float s = ssum[nt], q = ssq[nt];
    s += __shfl_xor(s, 16);
    q += __shfl_xor(q, 16);
    s += __shfl_xor(s, 32);
    q += __shfl_xor(q, 32);
    if (quad == 0) {
      const int n = n0 + nt * 16 + nl;
      atomicAdd(&stats[n], s);
      atomicAdd(&stats[128 + n], q);
    }
  }
}

// ---- BN finalize: per-feature scale/shift from sums (tiny; proven ~free in round 3)
__global__ __launch_bounds__(128) void bn_finalize(const float* __restrict__ stats,
                                                   const float* __restrict__ g,
                                                   const float* __restrict__ be,
                                                   float* __restrict__ scsh, float invN) {
  int f = threadIdx.x;
  float mu = stats[f] * invN;
  float var = stats[128 + f] * invN - mu * mu;
  float rstd = rsqrtf(var + 1e-5f);
  float sc = rstd * g[f];
  scsh[f] = sc;
  scsh[128 + f] = be[f] - mu * sc;
}

// ---- pooling (fused layer-3 BN+relu via precomputed scsh) + final head, one block/graph
__global__ __launch_bounds__(256) void pool_final(
    const u16* __restrict__ Hh, const int* __restrict__ batch, const float* __restrict__ scsh,
    const float* __restrict__ f1w, const float* __restrict__ f1b, const float* __restrict__ f2w,
    const float* __restrict__ f2b, float* __restrict__ out, int nrows) {
  __shared__ float red[16][128];
  __shared__ float pr[128];
  __shared__ float tt[128];
  const int gid = blockIdx.x, t = threadIdx.x;
  int l = 0, r = nrows;
  while (l < r) {
    int m = (l + r) >> 1;
    if (batch[m] < gid) l = m + 1; else r = m;
  }
  const int s0 = l;
  r = nrows;
  while (l < r) {
    int m = (l + r) >> 1;
    if (batch[m] < gid + 1) l = m + 1; else r = m;
  }
  const int s1 = l;
  const int fl = t & 15;
  const int grp = t >> 4;
  float sc[8], sh[8];
#pragma unroll
  for (int i = 0; i < 8; ++i) {
    sc[i] = scsh[fl * 8 + i];
    sh[i] = scsh[128 + fl * 8 + i];
  }
  float a[8];
#pragma unroll
  for (int i = 0; i < 8; ++i) a[i] = 0.f;
  for (int i = s0 + grp; i < s1; i += 16) {
    uint4 v = *(const uint4*)(Hh + (size_t)i * 128 + fl * 8);
    const u16* pp = (const u16*)&v;
#pragma unroll
    for (int k = 0; k < 8; ++k) {
      float xv = bf2f(pp[k]) * sc[k] + sh[k];
      a[k] += xv > 0.f ? xv : 0.f;
    }
  }
#pragma unroll
  for (int k = 0; k < 8; ++k) red[grp][fl * 8 + k] = a[k];
  __syncthreads();
  if (t < 128) {
    float s = 0.f;
#pragma unroll
    for (int gg2 = 0; gg2 < 16; ++gg2) s += red[gg2][t];
    pr[t] = s;
  }
  __syncthreads();
  if (t < 128) {
    float s = f1b[t];
    for (int k = 0; k < 128; ++k) s += pr[k] * f1w[k * 128 + t];
    tt[t] = s > 0.f ? s : 0.f;
  }
  __syncthreads();
  if (t < 10) {
    float s2 = f2b[t];
    for (int k = 0; k < 128; ++k) s2 += tt[k] * f2w[k * 10 + t];
    out[gid * 10 + t] = s2;
  }
}

// ws layout (bytes):
//   H     @ 0          : 25,600,000  (bf16 node features)
//   AGG   @ 25,600,000 : 25,600,000  (bf16 aggregated, layer input tiles)
//   PAIRS @ 51,200,000 : 512*4608*4 = 9,437,184
//   CSR   @ 60,637,184 : 9,437,184
//   RS    @ 70,074,368 : 400,000
//   DEG   @ 70,474,368 : 400,000
//   CUR   @ 70,874,368 : 2,048       (zeroed)
//   STATS @ 70,876,416 : 3,072       (3 layers x 256 f32; zeroed, contiguous w/ CUR)
//   SCSH  @ 70,879,488 : 3,072       (3 layers x 256 f32; written by bn_finalize)
//   WT    @ 70,882,560 : 196,608
//   TBL   @ 71,079,168 : 128,000
extern "C" void kernel_launch(void* const* d_in, const int* in_sizes, int n_in, void* d_out,
                              int out_size, void* d_ws, size_t ws_size, hipStream_t stream) {
  const int* x = (const int*)d_in[0];
  const int* ei = (const int*)d_in[1];
  const int* batch = (const int*)d_in[2];
  const float* emb = (const float*)d_in[3];
  const float* iw1 = (const float*)d_in[4];
  const float* ib1 = (const float*)d_in[5];
  const float* iw2 = (const float*)d_in[6];
  const float* ib2 = (const float*)d_in[7];
  const float* f1w = (const float*)d_in[8];
  const float* f1b = (const float*)d_in[9];
  const float* f2w = (const float*)d_in[10];
  const float* f2b = (const float*)d_in[11];
  const float* cw1[3] = {(const float*)d_in[12], (const float*)d_in[18], (const float*)d_in[24]};
  const float* cb1[3] = {(const float*)d_in[13], (const float*)d_in[19], (const float*)d_in[25]};
  const float* cw2[3] = {(const float*)d_in[14], (const float*)d_in[20], (const float*)d_in[26]};
  const float* cb2[3] = {(const float*)d_in[15], (const float*)d_in[21], (const float*)d_in[27]};
  const float* gg[3] = {(const float*)d_in[16], (const float*)d_in[22], (const float*)d_in[28]};
  const float* bb[3] = {(const float*)d_in[17], (const float*)d_in[23], (const float*)d_in[29]};

  const int N_ = in_sizes[0];
  const int E_ = in_sizes[1] / 2;
  const int V_ = in_sizes[3] / 128;
  const int G_ = out_size / 10;
  const int NBUC = (N_ + 255) >> 8;
  const float invN = 1.0f / (float)N_;

  char* ws = (char*)d_ws;
  u16* H = (u16*)(ws + 0);
  u16* AGG = (u16*)(ws + 25600000);
  u32* PAIRS = (u32*)(ws + 51200000);
  u32* CSR = (u32*)(ws + 60637184);
  int* RS = (int*)(ws + 70074368);
  int* DEG = (int*)(ws + 70474368);
  u32* CUR = (u32*)(ws + 70874368);
  float* STATS = (float*)(ws + 70876416);
  float* SCSH = (float*)(ws + 70879488);
  u16* WT = (u16*)(ws + 70882560);
  u16* TBL = (u16*)(ws + 71079168);

  hipMemsetAsync(ws + 70874368, 0, 5120, stream);  // CUR + STATS

  prep_w6<<<384, 256, 0, stream>>>(cw1[0], cw2[0], cw1[1], cw2[1], cw1[2], cw2[2], WT);
  mlp0_table<<<V_, 128, 0, stream>>>(emb, iw1, ib1, iw2, ib2, TBL);
  bucket_scatter<<<(E_ + EPB - 1) / EPB, 256, 0, stream>>>(ei, ei + E_, PAIRS, CUR, E_, NBUC);
  csr_build<<<NBUC, 256, 0, stream>>>(PAIRS, CUR, CSR, RS, DEG, N_);

  const int ablk = (N_ + 3) / 4;
  const int mblk = (N_ + 63) / 64;
  for (int l = 0; l < 3; ++l) {
    const u16* W1 = WT + (size_t)l * 32768;
    const u16* W2 = WT + (size_t)l * 32768 + 16384;
    if (l == 0)
      agg_kernel<0><<<ablk, 256, 0, stream>>>(TBL, x, CSR, RS, DEG, nullptr, AGG, N_);
    else
      agg_kernel<1><<<ablk, 256, 0, stream>>>(H, nullptr, CSR, RS, DEG, SCSH + (l - 1) * 256,
                                              AGG, N_);
    mlp_kernel<<<mblk, 256, 0, stream>>>(AGG, W1, cb1[l], W2, cb2[l], H, STATS + l * 256, N_);
    bn_finalize<<<1, 128, 0, stream>>>(STATS + l * 256, gg[l], bb[l], SCSH + l * 256, invN);
  }
  pool_final<<<G_, 256, 0, stream>>>(H, batch, SCSH + 2 * 256, f1w, f1b, f2w, f2b,
                                     (float*)d_out, N_);
}